// Round 4
// baseline (144.212 us; speedup 1.0000x reference)
//
#include <hip/hip_runtime.h>
#include <math.h>

#define BB 1024
#define DD 128
#define QQ 65536
#define CHUNK 32
#define THREADS 256
#define COLS_PER_BLOCK 256
#define F2G (BB / COLS_PER_BLOCK)   // 4
#define INV_T 14.285714285714286f
#define SCALE 20.609929155556627f   // (1/T) * log2(e)

typedef short short8 __attribute__((ext_vector_type(8)));
typedef float f32x4  __attribute__((ext_vector_type(4)));
typedef unsigned short us4 __attribute__((ext_vector_type(4)));

static __device__ __forceinline__ unsigned short bf16rne(float f) {
    union { float f; unsigned u; } v; v.f = f;
    unsigned r = (v.u + 0x7FFFu + ((v.u >> 16) & 1u)) >> 16;
    return (unsigned short)r;
}

static __device__ __forceinline__ short8 pack8s(float4 x, float4 y) { // scaled
    short8 r;
    r[0]=(short)bf16rne(x.x*SCALE); r[1]=(short)bf16rne(x.y*SCALE);
    r[2]=(short)bf16rne(x.z*SCALE); r[3]=(short)bf16rne(x.w*SCALE);
    r[4]=(short)bf16rne(y.x*SCALE); r[5]=(short)bf16rne(y.y*SCALE);
    r[6]=(short)bf16rne(y.z*SCALE); r[7]=(short)bf16rne(y.w*SCALE);
    return r;
}
static __device__ __forceinline__ short8 pack8(float4 x, float4 y) { // unscaled
    short8 r;
    r[0]=(short)bf16rne(x.x); r[1]=(short)bf16rne(x.y);
    r[2]=(short)bf16rne(x.z); r[3]=(short)bf16rne(x.w);
    r[4]=(short)bf16rne(y.x); r[5]=(short)bf16rne(y.y);
    r[6]=(short)bf16rne(y.z); r[7]=(short)bf16rne(y.w);
    return r;
}

// ---------- K0: cnt histogram, fsum scatter, srr dots, f2bf(scaled bf16) ----------
__global__ __launch_bounds__(256)
void k0_prep(const float* __restrict__ features, const int* __restrict__ labels,
             const int* __restrict__ queue_labels,
             float* __restrict__ fsum, int* __restrict__ cnt,
             float* __restrict__ srr, unsigned short* f2bf)
{
    int t = blockIdx.x * 256 + threadIdx.x;          // grid 256x256 = 65536
    {
        int lab = (t < BB) ? labels[t] : queue_labels[t - BB];
        atomicAdd(&cnt[lab], 1);
    }
    int r = t >> 6, lane = t & 63;                   // one wave per batch row
    float2 a = reinterpret_cast<const float2*>(features + (size_t)r * 2 * DD + DD)[lane];
    float2 b = reinterpret_cast<const float2*>(features + (size_t)r * 2 * DD)[lane];
    float p = a.x * b.x + a.y * b.y;
#pragma unroll
    for (int off = 32; off > 0; off >>= 1) p += __shfl_xor(p, off);
    if (lane == 0) srr[r] = p;
    int lab = labels[r];
    atomicAdd(&fsum[(size_t)lab * DD + 2 * lane],     a.x);
    atomicAdd(&fsum[(size_t)lab * DD + 2 * lane + 1], a.y);
    if (f2bf) {
        unsigned int packed = (unsigned int)bf16rne(a.x * SCALE)
                            | ((unsigned int)bf16rne(a.y * SCALE) << 16);
        reinterpret_cast<unsigned int*>(f2bf)[(size_t)r * (DD / 2) + lane] = packed;
    }
}

// ---------- K1: gather-dot (class term) + qbf/qlabn prebuild ----------
// half-wave (32 lanes, float4/lane) per row; 8 rows per half-wave; 1024 blocks.
template<int PRE>
__global__ __launch_bounds__(256)
void k1_gather(const float* __restrict__ features, const int* __restrict__ labels,
               const float* __restrict__ queue, const int* __restrict__ queue_labels,
               const float* __restrict__ fsum, const int* __restrict__ cnt,
               unsigned short* __restrict__ qbf, int* __restrict__ qlabn,
               float* __restrict__ S1)
{
    const int t    = blockIdx.x * 256 + threadIdx.x;
    const int half = t >> 5;              // 0..8191
    const int hl   = t & 31;
    const int lane = threadIdx.x & 63;
    float acc = 0.f;
#pragma unroll
    for (int it = 0; it < 8; ++it) {
        int j = half * 8 + it;
        int lab = (j < BB) ? labels[j] : queue_labels[j - BB];
        const float* src = (j < BB) ? (features + (size_t)j * 2 * DD)
                                    : (queue + (size_t)(j - BB) * DD);
        float4 v = reinterpret_cast<const float4*>(src)[hl];
        if (PRE) {
            us4 pk;
            pk[0] = bf16rne(v.x); pk[1] = bf16rne(v.y);
            pk[2] = bf16rne(v.z); pk[3] = bf16rne(v.w);
            *reinterpret_cast<us4*>(qbf + (size_t)j * DD + hl * 4) = pk;
            if (hl == 0) qlabn[j] = lab;
        }
        float4 f = reinterpret_cast<const float4*>(fsum + (size_t)lab * DD)[hl];
        float d = v.x * f.x + v.y * f.y + v.z * f.z + v.w * f.w;
#pragma unroll
        for (int off = 16; off > 0; off >>= 1) d += __shfl_xor(d, off);
        if (hl == 0) acc += d / (float)(cnt[lab] - 1);
    }
    acc += __shfl_xor(acc, 32);
    if (lane == 0) atomicAdd(S1, acc);
}

// ---------- main: tot/pose via MFMA, stats[col][slice][2] ----------
template<int PRE>
__global__ __launch_bounds__(THREADS)
void supcon_main(const float* __restrict__ features, const int* __restrict__ labels,
                 const float* __restrict__ queue, const int* __restrict__ queue_labels,
                 const unsigned short* __restrict__ qbf, const int* __restrict__ qlabn,
                 const unsigned short* __restrict__ f2bf,
                 float* __restrict__ stats, int nslices)
{
    __shared__ int4 ldsbuf[2][512];   // 2 x 8KB bf16 A-chunks [32][128], swizzled

    const int tid = threadIdx.x;
    const int l = tid & 63, w = tid >> 6;
    const int bid = blockIdx.x;
    const int slice = bid % nslices, f2g = bid / nslices;
    const int sliceRows = QQ / nslices;
    const int nchunks = sliceRows / CHUNK;
    const int colbase = f2g * COLS_PER_BLOCK + w * 64;

    // stationary B operand: 4x16 f2 cols, pre-scaled bf16
    short8 bf[4][4];
    int mylab[4];
#pragma unroll
    for (int b = 0; b < 4; ++b) {
        int r = colbase + b * 16 + (l & 15);
        mylab[b] = labels[r];
        if (PRE) {
            const unsigned short* fp = f2bf + (size_t)r * DD + ((l >> 4) * 8);
#pragma unroll
            for (int kk = 0; kk < 4; ++kk)
                bf[b][kk] = *reinterpret_cast<const short8*>(fp + kk * 32);
        } else {
            const float* fp = features + (size_t)r * 2 * DD + DD + ((l >> 4) * 8);
#pragma unroll
            for (int kk = 0; kk < 4; ++kk) {
                float4 x = *reinterpret_cast<const float4*>(fp + kk * 32);
                float4 y = *reinterpret_cast<const float4*>(fp + kk * 32 + 4);
                bf[b][kk] = pack8s(x, y);
            }
        }
    }

    float tot[4] = {0.f,0.f,0.f,0.f}, pose[4] = {0.f,0.f,0.f,0.f};

    const int srow = tid >> 3, sseg = tid & 7;
    const int swzs = (srow & 7) << 4;
    const int j0base = slice * sliceRows;

    // prologue: stage chunk 0
    {
        int j = j0base + srow;
        char* base = (char*)&ldsbuf[0][0] + srow * 256;
        int cb0 = (sseg * 32) ^ swzs;
        if (PRE) {
            const short8* src = reinterpret_cast<const short8*>(
                qbf + (size_t)j * DD + sseg * 16);
            *reinterpret_cast<short8*>(base + cb0)        = src[0];
            *reinterpret_cast<short8*>(base + (cb0 ^ 16)) = src[1];
        } else {
            const float* src = ((j < BB) ? (features + (size_t)j * 2 * DD)
                                         : (queue + (size_t)(j - BB) * DD)) + sseg * 16;
            float4 p0 = reinterpret_cast<const float4*>(src)[0];
            float4 p1 = reinterpret_cast<const float4*>(src)[1];
            float4 p2 = reinterpret_cast<const float4*>(src)[2];
            float4 p3 = reinterpret_cast<const float4*>(src)[3];
            *reinterpret_cast<short8*>(base + cb0)        = pack8(p0, p1);
            *reinterpret_cast<short8*>(base + (cb0 ^ 16)) = pack8(p2, p3);
        }
    }

    int cur = 0;
    for (int c = 0; c < nchunks; ++c) {
        __syncthreads();
        const int cj0 = j0base + c * CHUNK;
        const bool havenext = (c + 1 < nchunks);

        // issue next chunk's loads early (T14)
        short8 nlo, nhi;
        float4 p0, p1, p2, p3;
        if (havenext) {
            int j = cj0 + CHUNK + srow;
            if (PRE) {
                const short8* src = reinterpret_cast<const short8*>(
                    qbf + (size_t)j * DD + sseg * 16);
                nlo = src[0]; nhi = src[1];
            } else {
                const float* src = ((j < BB) ? (features + (size_t)j * 2 * DD)
                                             : (queue + (size_t)(j - BB) * DD)) + sseg * 16;
                p0 = reinterpret_cast<const float4*>(src)[0];
                p1 = reinterpret_cast<const float4*>(src)[1];
                p2 = reinterpret_cast<const float4*>(src)[2];
                p3 = reinterpret_cast<const float4*>(src)[3];
            }
        }

        // compute from buf[cur]
        const char* abase = (const char*)&ldsbuf[cur][0];
#pragma unroll
        for (int t2 = 0; t2 < 2; ++t2) {
            const int row = t2 * 16 + (l & 15);
            const char* rbase = abase + row * 256;
            const int g16 = (l >> 4) * 16;
            const int swz = (row & 7) << 4;
            const int j0 = cj0 + t2 * 16 + ((l >> 4) << 2);

            int4 ql4;
            if (PRE) ql4 = *reinterpret_cast<const int4*>(qlabn + j0);
            else ql4 = (j0 < BB) ? *reinterpret_cast<const int4*>(labels + j0)
                                 : *reinterpret_cast<const int4*>(queue_labels + (j0 - BB));
            const int* ql = reinterpret_cast<const int*>(&ql4);

            f32x4 acc[4];
#pragma unroll
            for (int b = 0; b < 4; ++b) acc[b] = f32x4{0.f,0.f,0.f,0.f};
#pragma unroll
            for (int kk = 0; kk < 4; ++kk) {
                short8 a = *reinterpret_cast<const short8*>(rbase + ((kk * 64 + g16) ^ swz));
#pragma unroll
                for (int b = 0; b < 4; ++b)
                    acc[b] = __builtin_amdgcn_mfma_f32_16x16x32_bf16(a, bf[b][kk], acc[b], 0, 0, 0);
            }
#pragma unroll
            for (int b = 0; b < 4; ++b) {
#pragma unroll
                for (int reg = 0; reg < 4; ++reg) {
                    float e = exp2f(acc[b][reg]);      // acc is already s*log2(e)
                    tot[b] += e;
                    pose[b] += (ql[reg] == mylab[b]) ? e : 0.f;
                }
            }
        }

        // write next chunk into other buffer
        if (havenext) {
            char* base = (char*)&ldsbuf[cur ^ 1][0] + srow * 256;
            int cb0 = (sseg * 32) ^ swzs;
            if (PRE) {
                *reinterpret_cast<short8*>(base + cb0)        = nlo;
                *reinterpret_cast<short8*>(base + (cb0 ^ 16)) = nhi;
            } else {
                *reinterpret_cast<short8*>(base + cb0)        = pack8(p0, p1);
                *reinterpret_cast<short8*>(base + (cb0 ^ 16)) = pack8(p2, p3);
            }
            cur ^= 1;
        }
    }

#pragma unroll
    for (int b = 0; b < 4; ++b) {
#pragma unroll
        for (int off = 16; off <= 32; off <<= 1) {
            tot[b]  += __shfl_xor(tot[b],  off);
            pose[b] += __shfl_xor(pose[b], off);
        }
    }
    if ((l >> 4) == 0) {
#pragma unroll
        for (int b = 0; b < 4; ++b) {
            float2 v; v.x = tot[b]; v.y = pose[b];
            *reinterpret_cast<float2*>(
                stats + ((size_t)(colbase + b * 16 + l) * nslices + slice) * 2) = v;
        }
    }
}

// ---------- F1: per-row finish (log terms), accumulate scalars ----------
__global__ __launch_bounds__(256)
void f1_rows(const float* __restrict__ stats, const float* __restrict__ srr,
             const int* __restrict__ cnt, const int* __restrict__ labels,
             float* __restrict__ accums, int nslices)
{
    __shared__ float red[4][2];
    int wv = threadIdx.x >> 6, lane = threadIdx.x & 63;
    int r = blockIdx.x * 4 + wv;
    float tot = 0.f, pose = 0.f;
    for (int s = lane; s < nslices; s += 64) {
        float2 v = reinterpret_cast<const float2*>(stats)[(size_t)r * nslices + s];
        tot += v.x; pose += v.y;
    }
#pragma unroll
    for (int off = 32; off > 0; off >>= 1) {
        tot  += __shfl_xor(tot,  off);
        pose += __shfl_xor(pose, off);
    }
    if (lane == 0) {
        float neg  = tot - pose;
        float srow = srr[r] * INV_T;
        float err  = expf(srow);
        float trip = srow - logf(tot - err);
        int   npq  = cnt[labels[r]] - 1;
        float p2   = srow / (float)npq + logf(neg);
        red[wv][0] = trip; red[wv][1] = p2;
    }
    __syncthreads();
    if (threadIdx.x == 0) {
        atomicAdd(&accums[0], red[0][0] + red[1][0] + red[2][0] + red[3][0]);
        atomicAdd(&accums[1], red[0][1] + red[1][1] + red[2][1] + red[3][1]);
    }
}

__global__ void f2_out(const float* __restrict__ accums, const float* __restrict__ S1,
                       float* __restrict__ out)
{
    if (threadIdx.x == 0) {
        float accT = accums[0], accP = accums[1], s1 = *S1;
        float selfl  = -accT / (float)BB;
        float classl = (-s1 * INV_T + accP) / (float)BB;
        out[0] = 0.5f * (selfl + classl);
        out[1] = selfl;
        out[2] = classl;
    }
}

extern "C" void kernel_launch(void* const* d_in, const int* in_sizes, int n_in,
                              void* d_out, int out_size, void* d_ws, size_t ws_size,
                              hipStream_t stream)
{
    const float* features     = (const float*)d_in[0];
    const int*   labels       = (const int*)  d_in[1];
    const float* queue        = (const float*)d_in[2];
    const int*   queue_labels = (const int*)  d_in[3];
    char* ws = (char*)d_ws;

    const size_t qbf_sz   = (size_t)QQ * DD * 2;   // 16 MB
    const size_t f2bf_sz  = (size_t)BB * DD * 2;   // 256 KB
    const size_t qlabn_sz = (size_t)QQ * 4;        // 256 KB
    const size_t fsum_sz  = (size_t)1024 * DD * 4; // 512 KB
    const size_t cnt_sz   = 4096;
    const size_t srr_sz   = 4096;
    const size_t scal_sz  = 256;
    const size_t tail_sz  = fsum_sz + cnt_sz + srr_sz + scal_sz;

    // prefer 512 slices; fall back to 256; fall back to non-prebuilt path
    int nslices = 512;
    bool pre = true;
    if (qbf_sz + f2bf_sz + qlabn_sz + (size_t)BB * 512 * 8 + tail_sz > ws_size) nslices = 256;
    if (qbf_sz + f2bf_sz + qlabn_sz + (size_t)BB * 256 * 8 + tail_sz > ws_size) {
        pre = false;
        nslices = 256;
        while ((size_t)BB * nslices * 8 + tail_sz > ws_size && nslices > 8)
            nslices >>= 1;
    }
    size_t stats_sz = (size_t)BB * nslices * 8;

    size_t off = 0;
    unsigned short* qbf = nullptr; unsigned short* f2bf = nullptr; int* qlabn = nullptr;
    if (pre) {
        qbf   = (unsigned short*)(ws + off); off += qbf_sz;
        f2bf  = (unsigned short*)(ws + off); off += f2bf_sz;
        qlabn = (int*)(ws + off);            off += qlabn_sz;
    }
    float* stats = (float*)(ws + off); off += stats_sz;
    float* fsum  = (float*)(ws + off); off += fsum_sz;
    int*   cnt   = (int*)(ws + off);   off += cnt_sz;
    float* srr   = (float*)(ws + off); off += srr_sz;
    float* scal  = (float*)(ws + off); // [0]=S1, [1]=accT, [2]=accP

    hipMemsetAsync((void*)fsum, 0, tail_sz, stream);

    k0_prep<<<dim3(256), dim3(256), 0, stream>>>(
        features, labels, queue_labels, fsum, cnt, srr, f2bf);

    if (pre)
        k1_gather<1><<<dim3(1024), dim3(256), 0, stream>>>(
            features, labels, queue, queue_labels, fsum, cnt, qbf, qlabn, scal);
    else
        k1_gather<0><<<dim3(1024), dim3(256), 0, stream>>>(
            features, labels, queue, queue_labels, fsum, cnt, qbf, qlabn, scal);

    dim3 grid(F2G * nslices);
    if (pre)
        supcon_main<1><<<grid, dim3(THREADS), 0, stream>>>(
            features, labels, queue, queue_labels, qbf, qlabn, f2bf, stats, nslices);
    else
        supcon_main<0><<<grid, dim3(THREADS), 0, stream>>>(
            features, labels, queue, queue_labels, qbf, qlabn, f2bf, stats, nslices);

    f1_rows<<<dim3(BB / 4), dim3(256), 0, stream>>>(stats, srr, cnt, labels, scal + 1, nslices);
    f2_out<<<dim3(1), dim3(64), 0, stream>>>(scal + 1, scal, (float*)d_out);
}

// Round 5
// 91.984 us; speedup vs baseline: 1.5678x; 1.5678x over previous
//
#include <hip/hip_runtime.h>
#include <math.h>

#define BB 1024
#define DD 128
#define QQ 65536
#define CHUNK 32
#define THREADS 256
#define COLS_PER_BLOCK 256
#define F2G (BB / COLS_PER_BLOCK)   // 4
#define NSLICES 256
#define INV_T 14.285714285714286f
#define SCALE 20.609929155556627f   // (1/T) * log2(e)
#define LN2F 0.6931471805599453f

typedef short short8 __attribute__((ext_vector_type(8)));
typedef float f32x4  __attribute__((ext_vector_type(4)));
typedef unsigned short us4 __attribute__((ext_vector_type(4)));

static __device__ __forceinline__ unsigned short bf16rne(float f) {
    union { float f; unsigned u; } v; v.f = f;
    unsigned r = (v.u + 0x7FFFu + ((v.u >> 16) & 1u)) >> 16;
    return (unsigned short)r;
}

static __device__ __forceinline__ short8 pack8s(float4 x, float4 y) { // scaled
    short8 r;
    r[0]=(short)bf16rne(x.x*SCALE); r[1]=(short)bf16rne(x.y*SCALE);
    r[2]=(short)bf16rne(x.z*SCALE); r[3]=(short)bf16rne(x.w*SCALE);
    r[4]=(short)bf16rne(y.x*SCALE); r[5]=(short)bf16rne(y.y*SCALE);
    r[6]=(short)bf16rne(y.z*SCALE); r[7]=(short)bf16rne(y.w*SCALE);
    return r;
}
static __device__ __forceinline__ short8 pack8(float4 x, float4 y) { // unscaled
    short8 r;
    r[0]=(short)bf16rne(x.x); r[1]=(short)bf16rne(x.y);
    r[2]=(short)bf16rne(x.z); r[3]=(short)bf16rne(x.w);
    r[4]=(short)bf16rne(y.x); r[5]=(short)bf16rne(y.y);
    r[6]=(short)bf16rne(y.z); r[7]=(short)bf16rne(y.w);
    return r;
}

// ---------- K0: cnt histogram, srr dots, f2bf (scaled bf16) ----------
__global__ __launch_bounds__(256)
void k0_prep(const float* __restrict__ features, const int* __restrict__ labels,
             const int* __restrict__ queue_labels,
             int* __restrict__ cnt, float* __restrict__ srr, unsigned short* f2bf)
{
    int t = blockIdx.x * 256 + threadIdx.x;          // grid 256x256 = 65536
    {
        int lab = (t < BB) ? labels[t] : queue_labels[t - BB];
        atomicAdd(&cnt[lab], 1);
    }
    int r = t >> 6, lane = t & 63;                   // one wave per batch row
    float2 a = reinterpret_cast<const float2*>(features + (size_t)r * 2 * DD + DD)[lane];
    float2 b = reinterpret_cast<const float2*>(features + (size_t)r * 2 * DD)[lane];
    float p = a.x * b.x + a.y * b.y;
#pragma unroll
    for (int off = 32; off > 0; off >>= 1) p += __shfl_xor(p, off);
    if (lane == 0) srr[r] = p;
    if (f2bf) {
        unsigned int packed = (unsigned int)bf16rne(a.x * SCALE)
                            | ((unsigned int)bf16rne(a.y * SCALE) << 16);
        reinterpret_cast<unsigned int*>(f2bf)[(size_t)r * (DD / 2) + lane] = packed;
    }
}

// ---------- K1: pure streaming convert: qbf (bf16 queue_new) + qlabn ----------
// grid 512 x 256 = 131072 threads; 16 us4 per thread, fully coalesced.
__global__ __launch_bounds__(256)
void k1_conv(const float* __restrict__ features, const int* __restrict__ labels,
             const float* __restrict__ queue, const int* __restrict__ queue_labels,
             unsigned short* __restrict__ qbf, int* __restrict__ qlabn)
{
    const int t = blockIdx.x * 256 + threadIdx.x;
    if (blockIdx.x < 256) {
        int j = t;  // t < 65536
        qlabn[j] = (j < BB) ? labels[j] : queue_labels[j - BB];
    }
#pragma unroll
    for (int k = 0; k < 16; ++k) {
        int u = k * 131072 + t;          // us4 index, 2M total
        int e = u * 4;                   // element index
        int row = e >> 7, col = e & 127;
        const float* src = (row < BB) ? (features + (size_t)row * 2 * DD + col)
                                      : (queue + (size_t)(e - BB * DD));
        float4 v = *reinterpret_cast<const float4*>(src);
        us4 pk;
        pk[0] = bf16rne(v.x); pk[1] = bf16rne(v.y);
        pk[2] = bf16rne(v.z); pk[3] = bf16rne(v.w);
        *reinterpret_cast<us4*>(qbf + (size_t)e) = pk;
    }
}

// ---------- main: tot/pose/psum via MFMA, stats[col][slice][4] ----------
template<int PRE>
__global__ __launch_bounds__(THREADS)
void supcon_main(const float* __restrict__ features, const int* __restrict__ labels,
                 const float* __restrict__ queue, const int* __restrict__ queue_labels,
                 const unsigned short* __restrict__ qbf, const int* __restrict__ qlabn,
                 const unsigned short* __restrict__ f2bf,
                 float* __restrict__ stats, int nslices)
{
    __shared__ int4 ldsbuf[2][512];   // 2 x 8KB bf16 A-chunks [32][128], swizzled

    const int tid = threadIdx.x;
    const int l = tid & 63, w = tid >> 6;
    const int bid = blockIdx.x;
    const int slice = bid % nslices, f2g = bid / nslices;
    const int sliceRows = QQ / nslices;
    const int nchunks = sliceRows / CHUNK;
    const int colbase = f2g * COLS_PER_BLOCK + w * 64;

    // stationary B operand: 4x16 f2 cols, pre-scaled bf16
    short8 bf[4][4];
    int mylab[4];
#pragma unroll
    for (int b = 0; b < 4; ++b) {
        int r = colbase + b * 16 + (l & 15);
        mylab[b] = labels[r];
        if (PRE) {
            const unsigned short* fp = f2bf + (size_t)r * DD + ((l >> 4) * 8);
#pragma unroll
            for (int kk = 0; kk < 4; ++kk)
                bf[b][kk] = *reinterpret_cast<const short8*>(fp + kk * 32);
        } else {
            const float* fp = features + (size_t)r * 2 * DD + DD + ((l >> 4) * 8);
#pragma unroll
            for (int kk = 0; kk < 4; ++kk) {
                float4 x = *reinterpret_cast<const float4*>(fp + kk * 32);
                float4 y = *reinterpret_cast<const float4*>(fp + kk * 32 + 4);
                bf[b][kk] = pack8s(x, y);
            }
        }
    }

    float tot[4]  = {0.f,0.f,0.f,0.f};
    float pose[4] = {0.f,0.f,0.f,0.f};
    float psum[4] = {0.f,0.f,0.f,0.f};

    const int srow = tid >> 3, sseg = tid & 7;
    const int swzs = (srow & 7) << 4;
    const int j0base = slice * sliceRows;

    // prologue: stage chunk 0
    {
        int j = j0base + srow;
        char* base = (char*)&ldsbuf[0][0] + srow * 256;
        int cb0 = (sseg * 32) ^ swzs;
        if (PRE) {
            const short8* src = reinterpret_cast<const short8*>(
                qbf + (size_t)j * DD + sseg * 16);
            *reinterpret_cast<short8*>(base + cb0)        = src[0];
            *reinterpret_cast<short8*>(base + (cb0 ^ 16)) = src[1];
        } else {
            const float* src = ((j < BB) ? (features + (size_t)j * 2 * DD)
                                         : (queue + (size_t)(j - BB) * DD)) + sseg * 16;
            float4 p0 = reinterpret_cast<const float4*>(src)[0];
            float4 p1 = reinterpret_cast<const float4*>(src)[1];
            float4 p2 = reinterpret_cast<const float4*>(src)[2];
            float4 p3 = reinterpret_cast<const float4*>(src)[3];
            *reinterpret_cast<short8*>(base + cb0)        = pack8(p0, p1);
            *reinterpret_cast<short8*>(base + (cb0 ^ 16)) = pack8(p2, p3);
        }
    }

    int cur = 0;
    for (int c = 0; c < nchunks; ++c) {
        __syncthreads();
        const int cj0 = j0base + c * CHUNK;
        const bool havenext = (c + 1 < nchunks);

        // issue next chunk's loads early (T14)
        short8 nlo, nhi;
        float4 p0, p1, p2, p3;
        if (havenext) {
            int j = cj0 + CHUNK + srow;
            if (PRE) {
                const short8* src = reinterpret_cast<const short8*>(
                    qbf + (size_t)j * DD + sseg * 16);
                nlo = src[0]; nhi = src[1];
            } else {
                const float* src = ((j < BB) ? (features + (size_t)j * 2 * DD)
                                             : (queue + (size_t)(j - BB) * DD)) + sseg * 16;
                p0 = reinterpret_cast<const float4*>(src)[0];
                p1 = reinterpret_cast<const float4*>(src)[1];
                p2 = reinterpret_cast<const float4*>(src)[2];
                p3 = reinterpret_cast<const float4*>(src)[3];
            }
        }

        // compute from buf[cur]
        const char* abase = (const char*)&ldsbuf[cur][0];
#pragma unroll
        for (int t2 = 0; t2 < 2; ++t2) {
            const int row = t2 * 16 + (l & 15);
            const char* rbase = abase + row * 256;
            const int g16 = (l >> 4) * 16;
            const int swz = (row & 7) << 4;
            const int j0 = cj0 + t2 * 16 + ((l >> 4) << 2);

            int4 ql4;
            if (PRE) ql4 = *reinterpret_cast<const int4*>(qlabn + j0);
            else ql4 = (j0 < BB) ? *reinterpret_cast<const int4*>(labels + j0)
                                 : *reinterpret_cast<const int4*>(queue_labels + (j0 - BB));
            const int* ql = reinterpret_cast<const int*>(&ql4);

            f32x4 acc[4];
#pragma unroll
            for (int b = 0; b < 4; ++b) acc[b] = f32x4{0.f,0.f,0.f,0.f};
#pragma unroll
            for (int kk = 0; kk < 4; ++kk) {
                short8 a = *reinterpret_cast<const short8*>(rbase + ((kk * 64 + g16) ^ swz));
#pragma unroll
                for (int b = 0; b < 4; ++b)
                    acc[b] = __builtin_amdgcn_mfma_f32_16x16x32_bf16(a, bf[b][kk], acc[b], 0, 0, 0);
            }
#pragma unroll
            for (int b = 0; b < 4; ++b) {
#pragma unroll
                for (int reg = 0; reg < 4; ++reg) {
                    float a = acc[b][reg];
                    float e = exp2f(a);                 // a = s * log2(e)
                    bool pos = (ql[reg] == mylab[b]);
                    tot[b]  += e;
                    pose[b] += pos ? e : 0.f;
                    psum[b] += pos ? a : 0.f;
                }
            }
        }

        // write next chunk into other buffer
        if (havenext) {
            char* base = (char*)&ldsbuf[cur ^ 1][0] + srow * 256;
            int cb0 = (sseg * 32) ^ swzs;
            if (PRE) {
                *reinterpret_cast<short8*>(base + cb0)        = nlo;
                *reinterpret_cast<short8*>(base + (cb0 ^ 16)) = nhi;
            } else {
                *reinterpret_cast<short8*>(base + cb0)        = pack8(p0, p1);
                *reinterpret_cast<short8*>(base + (cb0 ^ 16)) = pack8(p2, p3);
            }
            cur ^= 1;
        }
    }

#pragma unroll
    for (int b = 0; b < 4; ++b) {
#pragma unroll
        for (int off = 16; off <= 32; off <<= 1) {
            tot[b]  += __shfl_xor(tot[b],  off);
            pose[b] += __shfl_xor(pose[b], off);
            psum[b] += __shfl_xor(psum[b], off);
        }
    }
    if ((l >> 4) == 0) {
#pragma unroll
        for (int b = 0; b < 4; ++b) {
            float4 v; v.x = tot[b]; v.y = pose[b]; v.z = psum[b]; v.w = 0.f;
            *reinterpret_cast<float4*>(
                stats + ((size_t)(colbase + b * 16 + l) * nslices + slice) * 4) = v;
        }
    }
}

// ---------- F1: per-row finish (log terms), accumulate scalars ----------
__global__ __launch_bounds__(256)
void f1_rows(const float* __restrict__ stats, const float* __restrict__ srr,
             const int* __restrict__ cnt, const int* __restrict__ labels,
             float* __restrict__ accums, int nslices)
{
    __shared__ float red[4][2];
    int wv = threadIdx.x >> 6, lane = threadIdx.x & 63;
    int r = blockIdx.x * 4 + wv;
    float tot = 0.f, pose = 0.f, ps = 0.f;
    for (int s = lane; s < nslices; s += 64) {
        float4 v = reinterpret_cast<const float4*>(stats)[(size_t)r * nslices + s];
        tot += v.x; pose += v.y; ps += v.z;
    }
#pragma unroll
    for (int off = 32; off > 0; off >>= 1) {
        tot  += __shfl_xor(tot,  off);
        pose += __shfl_xor(pose, off);
        ps   += __shfl_xor(ps,   off);
    }
    if (lane == 0) {
        float neg  = tot - pose;
        float srow = srr[r] * INV_T;           // exact diag logit
        float trip = srow - logf(tot - expf(srow));
        float w    = 1.f / (float)(cnt[labels[r]] - 1);
        float mlpp = (ps * LN2F - srow) * w - logf(neg);
        red[wv][0] = trip; red[wv][1] = mlpp;
    }
    __syncthreads();
    if (threadIdx.x == 0) {
        atomicAdd(&accums[0], red[0][0] + red[1][0] + red[2][0] + red[3][0]);
        atomicAdd(&accums[1], red[0][1] + red[1][1] + red[2][1] + red[3][1]);
    }
}

__global__ void f2_out(const float* __restrict__ accums, float* __restrict__ out)
{
    if (threadIdx.x == 0) {
        float selfl  = -accums[0] / (float)BB;
        float classl = -accums[1] / (float)BB;
        out[0] = 0.5f * (selfl + classl);
        out[1] = selfl;
        out[2] = classl;
    }
}

extern "C" void kernel_launch(void* const* d_in, const int* in_sizes, int n_in,
                              void* d_out, int out_size, void* d_ws, size_t ws_size,
                              hipStream_t stream)
{
    const float* features     = (const float*)d_in[0];
    const int*   labels       = (const int*)  d_in[1];
    const float* queue        = (const float*)d_in[2];
    const int*   queue_labels = (const int*)  d_in[3];
    char* ws = (char*)d_ws;

    const size_t qbf_sz   = (size_t)QQ * DD * 2;   // 16 MB
    const size_t f2bf_sz  = (size_t)BB * DD * 2;   // 256 KB
    const size_t qlabn_sz = (size_t)QQ * 4;        // 256 KB
    const size_t cnt_sz   = 4096;
    const size_t srr_sz   = 4096;
    const size_t scal_sz  = 256;

    int nslices = NSLICES;
    size_t stats_sz = (size_t)BB * nslices * 16;
    bool pre = ws_size >= qbf_sz + f2bf_sz + qlabn_sz + stats_sz + cnt_sz + srr_sz + scal_sz;
    if (!pre) {
        while ((size_t)BB * nslices * 16 + cnt_sz + srr_sz + scal_sz > ws_size && nslices > 8)
            nslices >>= 1;
        stats_sz = (size_t)BB * nslices * 16;
    }

    size_t off = 0;
    unsigned short* qbf = nullptr; unsigned short* f2bf = nullptr; int* qlabn = nullptr;
    if (pre) {
        qbf   = (unsigned short*)(ws + off); off += qbf_sz;
        f2bf  = (unsigned short*)(ws + off); off += f2bf_sz;
        qlabn = (int*)(ws + off);            off += qlabn_sz;
    }
    float* stats = (float*)(ws + off); off += stats_sz;
    int*   cnt   = (int*)(ws + off);   off += cnt_sz;
    float* scal  = (float*)(ws + off); off += scal_sz;   // [0]=accT, [1]=accP
    float* srr   = (float*)(ws + off); off += srr_sz;

    hipMemsetAsync((void*)cnt, 0, cnt_sz + scal_sz, stream);

    k0_prep<<<dim3(256), dim3(256), 0, stream>>>(
        features, labels, queue_labels, cnt, srr, f2bf);

    if (pre)
        k1_conv<<<dim3(512), dim3(256), 0, stream>>>(
            features, labels, queue, queue_labels, qbf, qlabn);

    dim3 grid(F2G * nslices);
    if (pre)
        supcon_main<1><<<grid, dim3(THREADS), 0, stream>>>(
            features, labels, queue, queue_labels, qbf, qlabn, f2bf, stats, nslices);
    else
        supcon_main<0><<<grid, dim3(THREADS), 0, stream>>>(
            features, labels, queue, queue_labels, qbf, qlabn, f2bf, stats, nslices);

    f1_rows<<<dim3(BB / 4), dim3(256), 0, stream>>>(stats, srr, cnt, labels, scal, nslices);
    f2_out<<<dim3(1), dim3(64), 0, stream>>>(scal, (float*)d_out);
}